// Round 1
// baseline (169.500 us; speedup 1.0000x reference)
//
#include <hip/hip_runtime.h>
#include <hip/hip_bf16.h>
#include <cstdint>
#include <cstddef>

typedef unsigned short u16;
typedef __attribute__((ext_vector_type(8))) __bf16 bf16x8;
typedef __attribute__((ext_vector_type(4))) unsigned u32x4;
typedef __attribute__((ext_vector_type(16))) float f32x16;

#define LPOS 4096
#define CDIM 256
// per-buffer LDS (u16): 8192 K (32 rows x 256c) + 5120 V (4 planes x 160 rows x 8j)
#define LDSBUF 13312

#if __has_builtin(__builtin_amdgcn_exp2f)
#define EXP2(x) __builtin_amdgcn_exp2f(x)
#else
#define EXP2(x) exp2f(x)
#endif

// async global->LDS 16B: LDS dst must be wave-uniform base + lane*16
#define GLOAD_LDS16(g, l)                                                      \
  __builtin_amdgcn_global_load_lds(                                            \
      (const __attribute__((address_space(1))) void*)(g),                      \
      (__attribute__((address_space(3))) void*)(l), 16, 0, 0)

__device__ __forceinline__ unsigned f2bfbits(float x) {
  union { float f; unsigned u; } v; v.f = x;
  return (v.u + 0x7FFFu + ((v.u >> 16) & 1u)) >> 16;
}
__device__ __forceinline__ unsigned packbf(float a, float b) {
  __hip_bfloat162 h2 = __float22bfloat162_rn(make_float2(a, b));
  return *(unsigned*)&h2;
}

// ------- fused normalize: stats + normalize + transpose + bf16 cast --------
// Q (arr==0) is pre-scaled by log2(e): downstream uses exp2(Q.K) == exp(q.k).
__global__ void norm_fused(const float* __restrict__ t_in,
                           const float* __restrict__ s_in,
                           const float* __restrict__ r_in,
                           u16* __restrict__ qn, u16* __restrict__ ksn,
                           u16* __restrict__ krn) {
  __shared__ float tile[256 * 33];
  __shared__ float sums[256], sqs[256];
  __shared__ float mv[32], ivv[32];
  int idx = blockIdx.x;
  int ab = idx >> 7, lt = idx & 127;
  int arr = ab >> 1, b = ab & 1;
  int l0 = lt * 32;
  const float* inp = (arr == 0 ? t_in : arr == 1 ? s_in : r_in) + (size_t)b * CDIM * LPOS;
  u16* outp = (arr == 0 ? qn : arr == 1 ? ksn : krn) + (size_t)b * LPOS * CDIM;
  float scale = (arr == 0) ? 1.4426950408889634f : 1.0f;
  int t = threadIdx.x;
  int cg = t >> 5, l = t & 31;
  float sum = 0.f, sq = 0.f;
#pragma unroll 8
  for (int cc = 0; cc < 32; ++cc) {
    int c = cg * 32 + cc;
    float v = inp[(size_t)c * LPOS + l0 + l];
    tile[c * 33 + l] = v;
    sum += v; sq += v * v;
  }
  sums[t] = sum; sqs[t] = sq;
  __syncthreads();
  if (t < 32) {
    float s = 0.f, q = 0.f;
#pragma unroll
    for (int g = 0; g < 8; ++g) { s += sums[g * 32 + t]; q += sqs[g * 32 + t]; }
    float mean = s * (1.0f / CDIM);
    float nsq = q - s * s * (1.0f / CDIM);
    mv[t] = mean;
    ivv[t] = rsqrtf(fmaxf(nsq, 1e-20f)) * scale;
  }
  __syncthreads();
  int c2 = t & 127, ph = t >> 7;
#pragma unroll 4
  for (int rr = 0; rr < 16; ++rr) {
    int pos = ph + rr * 2;
    float m = mv[pos], iv = ivv[pos];
    float v0 = (tile[(2 * c2) * 33 + pos] - m) * iv;
    float v1 = (tile[(2 * c2 + 1) * 33 + pos] - m) * iv;
    *(unsigned*)&outp[(size_t)(l0 + pos) * CDIM + 2 * c2] = packbf(v0, v1);
  }
}

// ---------------- build combined V tensors (bf16, [C_v][L]) -----------------
// vs: [2][32][4096]   ch: 0..3 src_feats, 4 ones, 5..31 zero
// vr: [2][160][4096]  ch: 0..150 sem, 151..154 ref_feats, 155 ones, 156..159 zero
__global__ void build_v(const float* __restrict__ sf, const float* __restrict__ rf,
                        const float* __restrict__ sem,
                        u16* __restrict__ vs, u16* __restrict__ vr) {
  int t = blockIdx.x * 256 + threadIdx.x;
  const int NVS = 2 * 32 * 4096;
  if (t < NVS) {
    int b = t >> 17;
    int c = (t >> 12) & 31;
    int j = t & 4095;
    float v = (c < 4) ? sf[((size_t)b * 4 + c) * LPOS + j] : (c == 4 ? 1.0f : 0.0f);
    vs[t] = (u16)f2bfbits(v);
  } else {
    int t2 = t - NVS;
    if (t2 < 2 * 160 * 4096) {
      int b = t2 / (160 * 4096);
      int rr = t2 % (160 * 4096);
      int c = rr >> 12, j = rr & 4095;
      float v = (c < 151) ? sem[((size_t)b * 151 + c) * LPOS + j]
              : (c < 155) ? rf[((size_t)b * 4 + (c - 151)) * LPOS + j]
              : (c == 155) ? 1.0f : 0.0f;
      vr[((size_t)b * 160 + c) * LPOS + j] = (u16)f2bfbits(v);
    }
  }
}

// ---------------- fused flash soft-warp ----------------
// S^T orientation: D[m=j][n=i] = sum_c K[j][c] * Q[i][c]
// PV: D[m=c][n=i]  = sum_j V[c][j] * P[j][i]
// R9: depth-2 counted-vmcnt pipeline (T3/T4), raw s_barrier (no vmcnt drain).
//  - 3 LDS buffers (78 KB/block; 2 blocks = 156 KB <= 160 KB/CU, occupancy
//    unchanged). stage(jt+2) issued inside iter jt -> ~2 iterations of flight.
//  - FIFO invariant: at iter jt entry, outstanding = stage(jt)+stage(jt+1);
//    s_waitcnt vmcnt(|stage|) completes exactly stage(jt) (oldest), keeps the
//    rest in flight. Last iter: vmcnt(0) (stage(jt+1) was never issued).
//  - ref V-slot map rebalanced (s = wave + 4g -> per-wave stage counts
//    {7,7,6,6}) so the uniform vmcnt(6) is per-wave SAFE. Old map gave wave 3
//    only 5 loads -> vmcnt(7) would have raced on its own K rows.
//  - Overwrite race audit: stage(jt+2) targets buf[(jt+2)%3] == buf[(jt-1)%3],
//    last READ during iter jt-1; the s_barrier at jt proves all waves finished
//    jt-1. Cross-wave read-after-stage: each wave's own vmcnt wait is BEFORE
//    its barrier arrival, so post-barrier all waves' stage(jt) data is in LDS.
//  - src vf loads issue BEFORE stage(jt+2): compiler's wait-for-vf then only
//    drains loads OLDER than vf (FIFO), never the fresh prefetch.
template <int CT>
__device__ __forceinline__ void flash_body(
    const u16* __restrict__ qb, const u16* __restrict__ kb,
    const u16* __restrict__ vb, float* __restrict__ dst,
    u16 (*lds)[LDSBUF], int wave, int lane, int i_wave, int j_base, int iters) {
  int h = lane >> 5, ln = lane & 31;

  // Q fragments: B[k=c][n=i], lane n=ln, k = kt*16 + h*8 + t
  bf16x8 qf[16];
  const u16* qrow = qb + (size_t)(i_wave + ln) * CDIM;
#pragma unroll
  for (int kt = 0; kt < 16; ++kt)
    qf[kt] = *(const bf16x8*)(qrow + kt * 16 + h * 8);
  // pin: asm results cannot be rematerialized -> qf stays in VGPRs (R8)
#pragma unroll
  for (int kt = 0; kt < 16; ++kt)
    asm volatile("" : "+v"(*(u32x4*)&qf[kt]));

  f32x16 O[CT];
#pragma unroll
  for (int c = 0; c < CT; ++c)
#pragma unroll
    for (int t = 0; t < 16; ++t) O[c][t] = 0.0f;

  // Producer: K 32 rows (XOR-swizzled 16B chunks); ref also V as 10 x 64-row
  // slots over flat [plane(4)][row(160)][8j]. Slot->wave map: s = wave + 4g
  // (counts {3,3,2,2}) so every wave stages >= 6 items (4K + >=2V).
  auto stage = [&](int j0s, int buf) {
#pragma unroll
    for (int g = 0; g < 4; ++g) {
      int G = wave * 4 + g;
      int j = 2 * G + h;
      GLOAD_LDS16(kb + (size_t)(j0s + j) * CDIM + (ln ^ (j & 7)) * 8,
                  &lds[buf][G * 512]);
    }
    if constexpr (CT == 5) {
#pragma unroll
      for (int g = 0; g < 3; ++g) {
        int s = wave + g * 4;               // 0..11, use 0..9
        if (s < 10) {
          int f = s * 64 + lane;            // flat 16B-chunk index 0..639
          int p = f / 160;                  // plane = j-octet
          int c = f - p * 160;              // V channel row
          GLOAD_LDS16(vb + (size_t)c * LPOS + j0s + p * 8,
                      &lds[buf][8192 + s * 512]);
        }
      }
    }
  };

  // Precomputed LDS read bases (buf 0); runtime bo = buf*LDSBUF is added per
  // read (a handful of v_adds/iter; the costly R7 failure mode was qf
  // GLOBAL remat reloads, not address VALU).
  int kread_base = ln * 256 + 8 * (h ^ (ln & 1));
  int q = (ln >> 1) & 3;
  const u16* ka[4];
#pragma unroll
  for (int m = 0; m < 4; ++m) ka[m] = &lds[0][kread_base + 16 * (m ^ q)];
  // V(ref) addr(kt2,ct,buf) = va + kt2*2560 + ct*256 + bo
  const u16* va = &lds[0][8192 + h * 1280 + ln * 8];

  stage(j_base, 0);
  if (iters > 1) stage(j_base + 32, 1);

  int buf = 0;
  for (int jt = 0; jt < iters; ++jt) {
    int j0 = j_base + jt * 32;
    int bo = buf * LDSBUF;

    // Own stage(jt) completion (oldest in FIFO); keep newer prefetch flying.
    if (jt == iters - 1) {
      asm volatile("s_waitcnt vmcnt(0)" ::: "memory");
    } else if (CT == 5) {
      asm volatile("s_waitcnt vmcnt(6)" ::: "memory");
    } else {
      asm volatile("s_waitcnt vmcnt(4)" ::: "memory");
    }
    __builtin_amdgcn_sched_barrier(0);
    __builtin_amdgcn_s_barrier();      // raw: no vmcnt/lgkm drain
    __builtin_amdgcn_sched_barrier(0);

    // src: consumer V loads FIRST (FIFO: older than the new prefetch)
    bf16x8 vf[2];
    if constexpr (CT == 1) {
#pragma unroll
      for (int kt2 = 0; kt2 < 2; ++kt2)
        vf[kt2] = *(const bf16x8*)(vb + (size_t)ln * LPOS + j0 + (2 * kt2 + h) * 8);
    }
    if (jt + 2 < iters) {
      int b2 = buf ? buf - 1 : 2;        // (buf+2)%3
      stage(j0 + 64, b2);                // producer LAST
    }

    // QK: A = K (LDS), B = Q (pinned regs)
    f32x16 Sa, Sb;
#pragma unroll
    for (int t = 0; t < 16; ++t) { Sa[t] = 0.0f; Sb[t] = 0.0f; }
#pragma unroll
    for (int kt = 0; kt < 16; kt += 2) {
      bf16x8 ka0 = *(const bf16x8*)(ka[kt & 3] + 64 * (kt >> 2) + bo);
      Sa = __builtin_amdgcn_mfma_f32_32x32x16_bf16(ka0, qf[kt], Sa, 0, 0, 0);
      bf16x8 ka1 = *(const bf16x8*)(ka[(kt + 1) & 3] + 64 * ((kt + 1) >> 2) + bo);
      Sb = __builtin_amdgcn_mfma_f32_32x32x16_bf16(ka1, qf[kt + 1], Sb, 0, 0, 0);
    }
    // Q was pre-scaled by log2e: exp2(s_hat) == exp(s). Single v_exp_f32.
    f32x16 S;
#pragma unroll
    for (int t = 0; t < 16; ++t) S[t] = EXP2(Sa[t] + Sb[t]);

    // P^T C-layout -> PV B-frags. STATIC packs, u32 cndmask selects, xor-32.
    bf16x8 pb[2];
#pragma unroll
    for (int kh = 0; kh < 2; ++kh) {
      unsigned c0 = packbf(S[kh * 8 + 0], S[kh * 8 + 1]);
      unsigned c1 = packbf(S[kh * 8 + 2], S[kh * 8 + 3]);
      unsigned c2 = packbf(S[kh * 8 + 4], S[kh * 8 + 5]);
      unsigned c3 = packbf(S[kh * 8 + 6], S[kh * 8 + 7]);
      unsigned keep0 = h ? c2 : c0, keep1 = h ? c3 : c1;
      unsigned send0 = h ? c0 : c2, send1 = h ? c1 : c3;
      unsigned recv0 = (unsigned)__shfl_xor((int)send0, 32, 64);
      unsigned recv1 = (unsigned)__shfl_xor((int)send1, 32, 64);
      union { unsigned u[4]; bf16x8 v; } tmp;
      tmp.u[0] = h ? recv0 : keep0;
      tmp.u[1] = h ? recv1 : keep1;
      tmp.u[2] = h ? keep0 : recv0;
      tmp.u[3] = h ? keep1 : recv1;
      pb[kh] = tmp.v;
    }

    // PV: A = V (ref: LDS; src: regs), B = P
#pragma unroll
    for (int ct = 0; ct < CT; ++ct)
#pragma unroll
      for (int kt2 = 0; kt2 < 2; ++kt2) {
        bf16x8 vax;
        if constexpr (CT == 5)
          vax = *(const bf16x8*)(va + kt2 * 2560 + ct * 256 + bo);
        else
          vax = vf[kt2];
        O[ct] = __builtin_amdgcn_mfma_f32_32x32x16_bf16(vax, pb[kt2], O[ct], 0, 0, 0);
      }

    buf = (buf == 2) ? 0 : buf + 1;
  }

  // epilogue: D rows = c, cols = i. Trim never-read channels:
  // src uses c<5 (4 feats + ones), ref uses c<156 (151 sem + 4 feats + ones).
  const int climit = (CT == 1) ? 5 : 156;
#pragma unroll
  for (int ct = 0; ct < CT; ++ct)
#pragma unroll
    for (int t = 0; t < 16; ++t) {
      int c = ct * 32 + (t & 3) + 8 * (t >> 2) + 4 * h;
      if (c < climit)
        dst[(size_t)c * LPOS + i_wave + ln] = O[ct][t];
    }
}

// 78 KB LDS, (256,2): full 256-reg budget (R2/R6 proved any tighter cap
// spills qf/O through scratch at a 2x cost). 2 blocks/CU (156 KB LDS).
__global__ __launch_bounds__(256, 2) void flash(
    const u16* __restrict__ qn, const u16* __restrict__ ksn, const u16* __restrict__ krn,
    const u16* __restrict__ vs, const u16* __restrict__ vr,
    float* __restrict__ nsrc, float* __restrict__ nref,
    int nch_src, int nch_ref) {
  __shared__ u16 lds[3][LDSBUF];   // 78 KB
  int tid = threadIdx.x;
  int wave = tid >> 6, lane = tid & 63;
  int idx = blockIdx.x;
  int third = idx / 3, m = idx - third * 3;
  if (m == 0) {                      // ref block
    int r = third;
    int chunk = r >> 6, b = (r >> 5) & 1, wgi = r & 31;
    int jchunk = LPOS / nch_ref;
    flash_body<5>(qn + (size_t)b * LPOS * CDIM, krn + (size_t)b * LPOS * CDIM,
                  vr + (size_t)b * 160 * LPOS,
                  nref + (size_t)(chunk * 2 + b) * 160 * LPOS,
                  lds, wave, lane, wgi * 128 + wave * 32, chunk * jchunk,
                  jchunk / 32);
  } else {                           // src block
    int r = idx - third - 1;
    int chunk = r >> 6, b = (r >> 5) & 1, wgi = r & 31;
    int jchunk = LPOS / nch_src;
    flash_body<1>(qn + (size_t)b * LPOS * CDIM, ksn + (size_t)b * LPOS * CDIM,
                  vs + (size_t)b * 32 * LPOS,
                  nsrc + (size_t)(chunk * 2 + b) * 32 * LPOS,
                  lds, wave, lane, wgi * 128 + wave * 32, chunk * jchunk,
                  jchunk / 32);
  }
}

// ---------------- finalize: sum chunks, divide by ones-channel --------------
// float4-vectorized: 325632 float4 outputs (= 1302528 f32).
__global__ void finalize(const float* __restrict__ nsrc, const float* __restrict__ nref,
                         float* __restrict__ out, int nch_src, int nch_ref) {
  int v = blockIdx.x * 256 + threadIdx.x;
  if (v >= 325632) return;
  float nx = 0.f, ny = 0.f, nz = 0.f, nw = 0.f;
  float dx = 0.f, dy = 0.f, dz = 0.f, dw = 0.f;
  if (v < 8192) {                         // warped_src_feat [2][4][4096]
    int b = v >> 12, c = (v >> 10) & 3, i4 = v & 1023;
    for (int k = 0; k < nch_src; ++k) {
      const float* base = nsrc + ((size_t)(k * 2 + b) * 32) * LPOS;
      float4 n4 = ((const float4*)(base + (size_t)c * LPOS))[i4];
      float4 d4 = ((const float4*)(base + (size_t)4 * LPOS))[i4];
      nx += n4.x; ny += n4.y; nz += n4.z; nw += n4.w;
      dx += d4.x; dy += d4.y; dz += d4.z; dw += d4.w;
    }
  } else if (v < 16384) {                 // warped_ref_feat [2][4][4096]
    int v1 = v - 8192;
    int b = v1 >> 12, c = (v1 >> 10) & 3, i4 = v1 & 1023;
    for (int k = 0; k < nch_ref; ++k) {
      const float* base = nref + ((size_t)(k * 2 + b) * 160) * LPOS;
      float4 n4 = ((const float4*)(base + (size_t)(151 + c) * LPOS))[i4];
      float4 d4 = ((const float4*)(base + (size_t)155 * LPOS))[i4];
      nx += n4.x; ny += n4.y; nz += n4.z; nw += n4.w;
      dx += d4.x; dy += d4.y; dz += d4.z; dw += d4.w;
    }
  } else {                                // warped_ref_seg [2][151][4096]
    int v2 = v - 16384;
    int b = v2 / 154624;                  // 151 * 1024
    int rr = v2 - b * 154624;
    int c = rr >> 10, i4 = rr & 1023;
    for (int k = 0; k < nch_ref; ++k) {
      const float* base = nref + ((size_t)(k * 2 + b) * 160) * LPOS;
      float4 n4 = ((const float4*)(base + (size_t)c * LPOS))[i4];
      float4 d4 = ((const float4*)(base + (size_t)155 * LPOS))[i4];
      nx += n4.x; ny += n4.y; nz += n4.z; nw += n4.w;
      dx += d4.x; dy += d4.y; dz += d4.z; dw += d4.w;
    }
  }
  float4 r;
  r.x = nx / dx; r.y = ny / dy; r.z = nz / dz; r.w = nw / dw;
  ((float4*)out)[v] = r;
}

extern "C" void kernel_launch(void* const* d_in, const int* in_sizes, int n_in,
                              void* d_out, int out_size, void* d_ws, size_t ws_size,
                              hipStream_t stream) {
  const float* trg  = (const float*)d_in[0];
  const float* srcp = (const float*)d_in[1];
  const float* refp = (const float*)d_in[2];
  const float* sfeat = (const float*)d_in[3];
  const float* rfeat = (const float*)d_in[4];
  const float* rsem  = (const float*)d_in[5];
  float* out = (float*)d_out;

  char* ws = (char*)d_ws;
  size_t o = 0;
  auto alloc = [&](size_t bytes) -> char* {
    char* p = ws + o;
    o += (bytes + 255) & ~(size_t)255;
    return p;
  };
  u16* qn  = (u16*)alloc(2ull * LPOS * CDIM * 2);
  u16* ksn = (u16*)alloc(2ull * LPOS * CDIM * 2);
  u16* krn = (u16*)alloc(2ull * LPOS * CDIM * 2);
  u16* vs  = (u16*)alloc(2ull * 32 * LPOS * 2);
  u16* vr  = (u16*)alloc(2ull * 160 * LPOS * 2);

  size_t fixed = o;
  int nch_ref = 8;                       // nch_src = 2*nch_ref (keeps 1:2 grid)
  for (;;) {
    size_t need = fixed + 512 +
                  (size_t)(2 * nch_ref) * 2 * 32 * LPOS * 4 +
                  (size_t)nch_ref * 2 * 160 * LPOS * 4;
    if (need <= ws_size || nch_ref == 1) break;
    nch_ref >>= 1;
  }
  int nch_src = 2 * nch_ref;
  float* nsrc = (float*)alloc((size_t)nch_src * 2 * 32 * LPOS * 4);
  float* nref = (float*)alloc((size_t)nch_ref * 2 * 160 * LPOS * 4);

  hipLaunchKernelGGL(norm_fused, dim3(768), dim3(256), 0, stream,
                     trg, srcp, refp, qn, ksn, krn);
  hipLaunchKernelGGL(build_v, dim3(6144), dim3(256), 0, stream,
                     sfeat, rfeat, rsem, vs, vr);
  hipLaunchKernelGGL(flash, dim3(64 * nch_ref * 3), dim3(256), 0, stream,
                     qn, ksn, krn, vs, vr, nsrc, nref, nch_src, nch_ref);
  hipLaunchKernelGGL(finalize, dim3(1272), dim3(256), 0, stream,
                     nsrc, nref, out, nch_src, nch_ref);
}

// Round 2
// 164.390 us; speedup vs baseline: 1.0311x; 1.0311x over previous
//
#include <hip/hip_runtime.h>
#include <hip/hip_bf16.h>
#include <cstdint>
#include <cstddef>

typedef unsigned short u16;
typedef __attribute__((ext_vector_type(8))) __bf16 bf16x8;
typedef __attribute__((ext_vector_type(4))) unsigned u32x4;
typedef __attribute__((ext_vector_type(16))) float f32x16;

#define LPOS 4096
#define CDIM 256
// per-buffer LDS (u16): 8192 K (32 rows x 256c) + 5120 V (4 planes x 160 rows x 8j)
#define LDSBUF 13312

#if __has_builtin(__builtin_amdgcn_exp2f)
#define EXP2(x) __builtin_amdgcn_exp2f(x)
#else
#define EXP2(x) exp2f(x)
#endif

// async global->LDS 16B: LDS dst must be wave-uniform base + lane*16
#define GLOAD_LDS16(g, l)                                                      \
  __builtin_amdgcn_global_load_lds(                                            \
      (const __attribute__((address_space(1))) void*)(g),                      \
      (__attribute__((address_space(3))) void*)(l), 16, 0, 0)

__device__ __forceinline__ unsigned f2bfbits(float x) {
  union { float f; unsigned u; } v; v.f = x;
  return (v.u + 0x7FFFu + ((v.u >> 16) & 1u)) >> 16;
}
__device__ __forceinline__ unsigned packbf(float a, float b) {
  __hip_bfloat162 h2 = __float22bfloat162_rn(make_float2(a, b));
  return *(unsigned*)&h2;
}

// ------- fused normalize: stats + normalize + transpose + bf16 cast --------
// Q (arr==0) is pre-scaled by log2(e): downstream uses exp2(Q.K) == exp(q.k).
__global__ void norm_fused(const float* __restrict__ t_in,
                           const float* __restrict__ s_in,
                           const float* __restrict__ r_in,
                           u16* __restrict__ qn, u16* __restrict__ ksn,
                           u16* __restrict__ krn) {
  __shared__ float tile[256 * 33];
  __shared__ float sums[256], sqs[256];
  __shared__ float mv[32], ivv[32];
  int idx = blockIdx.x;
  int ab = idx >> 7, lt = idx & 127;
  int arr = ab >> 1, b = ab & 1;
  int l0 = lt * 32;
  const float* inp = (arr == 0 ? t_in : arr == 1 ? s_in : r_in) + (size_t)b * CDIM * LPOS;
  u16* outp = (arr == 0 ? qn : arr == 1 ? ksn : krn) + (size_t)b * LPOS * CDIM;
  float scale = (arr == 0) ? 1.4426950408889634f : 1.0f;
  int t = threadIdx.x;
  int cg = t >> 5, l = t & 31;
  float sum = 0.f, sq = 0.f;
#pragma unroll 8
  for (int cc = 0; cc < 32; ++cc) {
    int c = cg * 32 + cc;
    float v = inp[(size_t)c * LPOS + l0 + l];
    tile[c * 33 + l] = v;
    sum += v; sq += v * v;
  }
  sums[t] = sum; sqs[t] = sq;
  __syncthreads();
  if (t < 32) {
    float s = 0.f, q = 0.f;
#pragma unroll
    for (int g = 0; g < 8; ++g) { s += sums[g * 32 + t]; q += sqs[g * 32 + t]; }
    float mean = s * (1.0f / CDIM);
    float nsq = q - s * s * (1.0f / CDIM);
    mv[t] = mean;
    ivv[t] = rsqrtf(fmaxf(nsq, 1e-20f)) * scale;
  }
  __syncthreads();
  int c2 = t & 127, ph = t >> 7;
#pragma unroll 4
  for (int rr = 0; rr < 16; ++rr) {
    int pos = ph + rr * 2;
    float m = mv[pos], iv = ivv[pos];
    float v0 = (tile[(2 * c2) * 33 + pos] - m) * iv;
    float v1 = (tile[(2 * c2 + 1) * 33 + pos] - m) * iv;
    *(unsigned*)&outp[(size_t)(l0 + pos) * CDIM + 2 * c2] = packbf(v0, v1);
  }
}

// ---------------- build combined V tensors (bf16, [C_v][L]) -----------------
// vs: [2][32][4096]   ch: 0..3 src_feats, 4 ones, 5..31 zero
// vr: [2][160][4096]  ch: 0..150 sem, 151..154 ref_feats, 155 ones, 156..159 zero
__global__ void build_v(const float* __restrict__ sf, const float* __restrict__ rf,
                        const float* __restrict__ sem,
                        u16* __restrict__ vs, u16* __restrict__ vr) {
  int t = blockIdx.x * 256 + threadIdx.x;
  const int NVS = 2 * 32 * 4096;
  if (t < NVS) {
    int b = t >> 17;
    int c = (t >> 12) & 31;
    int j = t & 4095;
    float v = (c < 4) ? sf[((size_t)b * 4 + c) * LPOS + j] : (c == 4 ? 1.0f : 0.0f);
    vs[t] = (u16)f2bfbits(v);
  } else {
    int t2 = t - NVS;
    if (t2 < 2 * 160 * 4096) {
      int b = t2 / (160 * 4096);
      int rr = t2 % (160 * 4096);
      int c = rr >> 12, j = rr & 4095;
      float v = (c < 151) ? sem[((size_t)b * 151 + c) * LPOS + j]
              : (c < 155) ? rf[((size_t)b * 4 + (c - 151)) * LPOS + j]
              : (c == 155) ? 1.0f : 0.0f;
      vr[((size_t)b * 160 + c) * LPOS + j] = (u16)f2bfbits(v);
    }
  }
}

// ---------------- fused flash soft-warp ----------------
// S^T orientation: D[m=j][n=i] = sum_c K[j][c] * Q[i][c]
// PV: D[m=c][n=i]  = sum_j V[c][j] * P[j][i]
// R10: per-wave latency attack (R9's deeper pipeline was NULL -> loads were
// already covered; the serial chain QK->exp->PACK->PV is the cost at 2
// waves/SIMD reg-capped occupancy).
//  (a) v_permlane32_swap_b32 replaces the 4 __shfl_xor(.,32) LDS-crossbar ops
//      + 16 cndmasks per iter. Gold layout: u[0]=[c0.lo,c2.lo^], u[2]=
//      [c0.hi_v,c2.hi]; swap(c0,c2) yields exactly (u0,u2); swap(c1,c3) ->
//      (u1,u3). Pure VALU: no lgkm latency, no LDS bank conflicts
//      (SQ_LDS_BANK_CONFLICT 4.19M was exactly 4 shfl x 65536 wave-iters x 16).
//  (b) s_setprio(1) across the compute section (T5): counted-vmcnt schedule
//      gives waves phase diversity -> scheduler can favor the compute wave.
template <int CT>
__device__ __forceinline__ void flash_body(
    const u16* __restrict__ qb, const u16* __restrict__ kb,
    const u16* __restrict__ vb, float* __restrict__ dst,
    u16 (*lds)[LDSBUF], int wave, int lane, int i_wave, int j_base, int iters) {
  int h = lane >> 5, ln = lane & 31;

  // Q fragments: B[k=c][n=i], lane n=ln, k = kt*16 + h*8 + t
  bf16x8 qf[16];
  const u16* qrow = qb + (size_t)(i_wave + ln) * CDIM;
#pragma unroll
  for (int kt = 0; kt < 16; ++kt)
    qf[kt] = *(const bf16x8*)(qrow + kt * 16 + h * 8);
  // pin: asm results cannot be rematerialized -> qf stays in VGPRs (R8)
#pragma unroll
  for (int kt = 0; kt < 16; ++kt)
    asm volatile("" : "+v"(*(u32x4*)&qf[kt]));

  f32x16 O[CT];
#pragma unroll
  for (int c = 0; c < CT; ++c)
#pragma unroll
    for (int t = 0; t < 16; ++t) O[c][t] = 0.0f;

  // Producer: K 32 rows (XOR-swizzled 16B chunks); ref also V as 10 x 64-row
  // slots over flat [plane(4)][row(160)][8j]. Slot->wave map: s = wave + 4g
  // (counts {3,3,2,2}) so every wave stages >= 6 items (4K + >=2V).
  auto stage = [&](int j0s, int buf) {
#pragma unroll
    for (int g = 0; g < 4; ++g) {
      int G = wave * 4 + g;
      int j = 2 * G + h;
      GLOAD_LDS16(kb + (size_t)(j0s + j) * CDIM + (ln ^ (j & 7)) * 8,
                  &lds[buf][G * 512]);
    }
    if constexpr (CT == 5) {
#pragma unroll
      for (int g = 0; g < 3; ++g) {
        int s = wave + g * 4;               // 0..11, use 0..9
        if (s < 10) {
          int f = s * 64 + lane;            // flat 16B-chunk index 0..639
          int p = f / 160;                  // plane = j-octet
          int c = f - p * 160;              // V channel row
          GLOAD_LDS16(vb + (size_t)c * LPOS + j0s + p * 8,
                      &lds[buf][8192 + s * 512]);
        }
      }
    }
  };

  // Precomputed LDS read bases (buf 0); runtime bo = buf*LDSBUF added per read.
  int kread_base = ln * 256 + 8 * (h ^ (ln & 1));
  int q = (ln >> 1) & 3;
  const u16* ka[4];
#pragma unroll
  for (int m = 0; m < 4; ++m) ka[m] = &lds[0][kread_base + 16 * (m ^ q)];
  // V(ref) addr(kt2,ct,buf) = va + kt2*2560 + ct*256 + bo
  const u16* va = &lds[0][8192 + h * 1280 + ln * 8];

  stage(j_base, 0);
  if (iters > 1) stage(j_base + 32, 1);

  int buf = 0;
  for (int jt = 0; jt < iters; ++jt) {
    int j0 = j_base + jt * 32;
    int bo = buf * LDSBUF;

    // Own stage(jt) completion (oldest in FIFO); keep newer prefetch flying.
    if (jt == iters - 1) {
      asm volatile("s_waitcnt vmcnt(0)" ::: "memory");
    } else if (CT == 5) {
      asm volatile("s_waitcnt vmcnt(6)" ::: "memory");
    } else {
      asm volatile("s_waitcnt vmcnt(4)" ::: "memory");
    }
    __builtin_amdgcn_sched_barrier(0);
    __builtin_amdgcn_s_barrier();      // raw: no vmcnt/lgkm drain
    __builtin_amdgcn_sched_barrier(0);

    // src: consumer V loads FIRST (FIFO: older than the new prefetch)
    bf16x8 vf[2];
    if constexpr (CT == 1) {
#pragma unroll
      for (int kt2 = 0; kt2 < 2; ++kt2)
        vf[kt2] = *(const bf16x8*)(vb + (size_t)ln * LPOS + j0 + (2 * kt2 + h) * 8);
    }
    if (jt + 2 < iters) {
      int b2 = buf ? buf - 1 : 2;        // (buf+2)%3
      stage(j0 + 64, b2);                // producer LAST
    }

    __builtin_amdgcn_s_setprio(1);       // T5: favor compute wave

    // QK: A = K (LDS), B = Q (pinned regs)
    f32x16 Sa, Sb;
#pragma unroll
    for (int t = 0; t < 16; ++t) { Sa[t] = 0.0f; Sb[t] = 0.0f; }
#pragma unroll
    for (int kt = 0; kt < 16; kt += 2) {
      bf16x8 ka0 = *(const bf16x8*)(ka[kt & 3] + 64 * (kt >> 2) + bo);
      Sa = __builtin_amdgcn_mfma_f32_32x32x16_bf16(ka0, qf[kt], Sa, 0, 0, 0);
      bf16x8 ka1 = *(const bf16x8*)(ka[(kt + 1) & 3] + 64 * ((kt + 1) >> 2) + bo);
      Sb = __builtin_amdgcn_mfma_f32_32x32x16_bf16(ka1, qf[kt + 1], Sb, 0, 0, 0);
    }
    // Q was pre-scaled by log2e: exp2(s_hat) == exp(s). Single v_exp_f32.
    f32x16 S;
#pragma unroll
    for (int t = 0; t < 16; ++t) S[t] = EXP2(Sa[t] + Sb[t]);

    // P^T C-layout -> PV B-frags via v_permlane32_swap_b32 (pure VALU):
    // swap(c0,c2): c0 -> [c0.lo, c2.lo^] = u[0], c2 -> [c0.hi_v, c2.hi] = u[2]
    bf16x8 pb[2];
#pragma unroll
    for (int kh = 0; kh < 2; ++kh) {
      unsigned c0 = packbf(S[kh * 8 + 0], S[kh * 8 + 1]);
      unsigned c1 = packbf(S[kh * 8 + 2], S[kh * 8 + 3]);
      unsigned c2 = packbf(S[kh * 8 + 4], S[kh * 8 + 5]);
      unsigned c3 = packbf(S[kh * 8 + 6], S[kh * 8 + 7]);
      asm("v_permlane32_swap_b32 %0, %1" : "+v"(c0), "+v"(c2));
      asm("v_permlane32_swap_b32 %0, %1" : "+v"(c1), "+v"(c3));
      union { unsigned u[4]; bf16x8 v; } tmp;
      tmp.u[0] = c0;
      tmp.u[1] = c1;
      tmp.u[2] = c2;
      tmp.u[3] = c3;
      pb[kh] = tmp.v;
    }

    // PV: A = V (ref: LDS; src: regs), B = P
#pragma unroll
    for (int ct = 0; ct < CT; ++ct)
#pragma unroll
      for (int kt2 = 0; kt2 < 2; ++kt2) {
        bf16x8 vax;
        if constexpr (CT == 5)
          vax = *(const bf16x8*)(va + kt2 * 2560 + ct * 256 + bo);
        else
          vax = vf[kt2];
        O[ct] = __builtin_amdgcn_mfma_f32_32x32x16_bf16(vax, pb[kt2], O[ct], 0, 0, 0);
      }

    __builtin_amdgcn_s_setprio(0);

    buf = (buf == 2) ? 0 : buf + 1;
  }

  // epilogue: D rows = c, cols = i. Trim never-read channels:
  // src uses c<5 (4 feats + ones), ref uses c<156 (151 sem + 4 feats + ones).
  const int climit = (CT == 1) ? 5 : 156;
#pragma unroll
  for (int ct = 0; ct < CT; ++ct)
#pragma unroll
    for (int t = 0; t < 16; ++t) {
      int c = ct * 32 + (t & 3) + 8 * (t >> 2) + 4 * h;
      if (c < climit)
        dst[(size_t)c * LPOS + i_wave + ln] = O[ct][t];
    }
}

// 78 KB LDS, (256,2): full 256-reg budget (R2/R6 proved any tighter cap
// spills qf/O through scratch at a 2x cost). 2 blocks/CU (156 KB LDS).
__global__ __launch_bounds__(256, 2) void flash(
    const u16* __restrict__ qn, const u16* __restrict__ ksn, const u16* __restrict__ krn,
    const u16* __restrict__ vs, const u16* __restrict__ vr,
    float* __restrict__ nsrc, float* __restrict__ nref,
    int nch_src, int nch_ref) {
  __shared__ u16 lds[3][LDSBUF];   // 78 KB
  int tid = threadIdx.x;
  int wave = tid >> 6, lane = tid & 63;
  int idx = blockIdx.x;
  int third = idx / 3, m = idx - third * 3;
  if (m == 0) {                      // ref block
    int r = third;
    int chunk = r >> 6, b = (r >> 5) & 1, wgi = r & 31;
    int jchunk = LPOS / nch_ref;
    flash_body<5>(qn + (size_t)b * LPOS * CDIM, krn + (size_t)b * LPOS * CDIM,
                  vr + (size_t)b * 160 * LPOS,
                  nref + (size_t)(chunk * 2 + b) * 160 * LPOS,
                  lds, wave, lane, wgi * 128 + wave * 32, chunk * jchunk,
                  jchunk / 32);
  } else {                           // src block
    int r = idx - third - 1;
    int chunk = r >> 6, b = (r >> 5) & 1, wgi = r & 31;
    int jchunk = LPOS / nch_src;
    flash_body<1>(qn + (size_t)b * LPOS * CDIM, ksn + (size_t)b * LPOS * CDIM,
                  vs + (size_t)b * 32 * LPOS,
                  nsrc + (size_t)(chunk * 2 + b) * 32 * LPOS,
                  lds, wave, lane, wgi * 128 + wave * 32, chunk * jchunk,
                  jchunk / 32);
  }
}

// ---------------- finalize: sum chunks, divide by ones-channel --------------
// float4-vectorized: 325632 float4 outputs (= 1302528 f32).
__global__ void finalize(const float* __restrict__ nsrc, const float* __restrict__ nref,
                         float* __restrict__ out, int nch_src, int nch_ref) {
  int v = blockIdx.x * 256 + threadIdx.x;
  if (v >= 325632) return;
  float nx = 0.f, ny = 0.f, nz = 0.f, nw = 0.f;
  float dx = 0.f, dy = 0.f, dz = 0.f, dw = 0.f;
  if (v < 8192) {                         // warped_src_feat [2][4][4096]
    int b = v >> 12, c = (v >> 10) & 3, i4 = v & 1023;
    for (int k = 0; k < nch_src; ++k) {
      const float* base = nsrc + ((size_t)(k * 2 + b) * 32) * LPOS;
      float4 n4 = ((const float4*)(base + (size_t)c * LPOS))[i4];
      float4 d4 = ((const float4*)(base + (size_t)4 * LPOS))[i4];
      nx += n4.x; ny += n4.y; nz += n4.z; nw += n4.w;
      dx += d4.x; dy += d4.y; dz += d4.z; dw += d4.w;
    }
  } else if (v < 16384) {                 // warped_ref_feat [2][4][4096]
    int v1 = v - 8192;
    int b = v1 >> 12, c = (v1 >> 10) & 3, i4 = v1 & 1023;
    for (int k = 0; k < nch_ref; ++k) {
      const float* base = nref + ((size_t)(k * 2 + b) * 160) * LPOS;
      float4 n4 = ((const float4*)(base + (size_t)(151 + c) * LPOS))[i4];
      float4 d4 = ((const float4*)(base + (size_t)155 * LPOS))[i4];
      nx += n4.x; ny += n4.y; nz += n4.z; nw += n4.w;
      dx += d4.x; dy += d4.y; dz += d4.z; dw += d4.w;
    }
  } else {                                // warped_ref_seg [2][151][4096]
    int v2 = v - 16384;
    int b = v2 / 154624;                  // 151 * 1024
    int rr = v2 - b * 154624;
    int c = rr >> 10, i4 = rr & 1023;
    for (int k = 0; k < nch_ref; ++k) {
      const float* base = nref + ((size_t)(k * 2 + b) * 160) * LPOS;
      float4 n4 = ((const float4*)(base + (size_t)c * LPOS))[i4];
      float4 d4 = ((const float4*)(base + (size_t)155 * LPOS))[i4];
      nx += n4.x; ny += n4.y; nz += n4.z; nw += n4.w;
      dx += d4.x; dy += d4.y; dz += d4.z; dw += d4.w;
    }
  }
  float4 r;
  r.x = nx / dx; r.y = ny / dy; r.z = nz / dz; r.w = nw / dw;
  ((float4*)out)[v] = r;
}

extern "C" void kernel_launch(void* const* d_in, const int* in_sizes, int n_in,
                              void* d_out, int out_size, void* d_ws, size_t ws_size,
                              hipStream_t stream) {
  const float* trg  = (const float*)d_in[0];
  const float* srcp = (const float*)d_in[1];
  const float* refp = (const float*)d_in[2];
  const float* sfeat = (const float*)d_in[3];
  const float* rfeat = (const float*)d_in[4];
  const float* rsem  = (const float*)d_in[5];
  float* out = (float*)d_out;

  char* ws = (char*)d_ws;
  size_t o = 0;
  auto alloc = [&](size_t bytes) -> char* {
    char* p = ws + o;
    o += (bytes + 255) & ~(size_t)255;
    return p;
  };
  u16* qn  = (u16*)alloc(2ull * LPOS * CDIM * 2);
  u16* ksn = (u16*)alloc(2ull * LPOS * CDIM * 2);
  u16* krn = (u16*)alloc(2ull * LPOS * CDIM * 2);
  u16* vs  = (u16*)alloc(2ull * 32 * LPOS * 2);
  u16* vr  = (u16*)alloc(2ull * 160 * LPOS * 2);

  size_t fixed = o;
  int nch_ref = 8;                       // nch_src = 2*nch_ref (keeps 1:2 grid)
  for (;;) {
    size_t need = fixed + 512 +
                  (size_t)(2 * nch_ref) * 2 * 32 * LPOS * 4 +
                  (size_t)nch_ref * 2 * 160 * LPOS * 4;
    if (need <= ws_size || nch_ref == 1) break;
    nch_ref >>= 1;
  }
  int nch_src = 2 * nch_ref;
  float* nsrc = (float*)alloc((size_t)nch_src * 2 * 32 * LPOS * 4);
  float* nref = (float*)alloc((size_t)nch_ref * 2 * 160 * LPOS * 4);

  hipLaunchKernelGGL(norm_fused, dim3(768), dim3(256), 0, stream,
                     trg, srcp, refp, qn, ksn, krn);
  hipLaunchKernelGGL(build_v, dim3(6144), dim3(256), 0, stream,
                     sfeat, rfeat, rsem, vs, vr);
  hipLaunchKernelGGL(flash, dim3(64 * nch_ref * 3), dim3(256), 0, stream,
                     qn, ksn, krn, vs, vr, nsrc, nref, nch_src, nch_ref);
  hipLaunchKernelGGL(finalize, dim3(1272), dim3(256), 0, stream,
                     nsrc, nref, out, nch_src, nch_ref);
}

// Round 3
// 147.107 us; speedup vs baseline: 1.1522x; 1.1175x over previous
//
#include <hip/hip_runtime.h>
#include <hip/hip_bf16.h>
#include <cstdint>
#include <cstddef>

typedef unsigned short u16;
typedef __attribute__((ext_vector_type(8))) __bf16 bf16x8;
typedef __attribute__((ext_vector_type(4))) unsigned u32x4;
typedef __attribute__((ext_vector_type(16))) float f32x16;

#define LPOS 4096
#define CDIM 256
// per-buffer LDS (u16): 8192 K (32 rows x 256c) + 5120 V (4 planes x 160 rows x 8j)
#define LDSBUF 13312

#if __has_builtin(__builtin_amdgcn_exp2f)
#define EXP2(x) __builtin_amdgcn_exp2f(x)
#else
#define EXP2(x) exp2f(x)
#endif

// async global->LDS 16B: LDS dst must be wave-uniform base + lane*16
#define GLOAD_LDS16(g, l)                                                      \
  __builtin_amdgcn_global_load_lds(                                            \
      (const __attribute__((address_space(1))) void*)(g),                      \
      (__attribute__((address_space(3))) void*)(l), 16, 0, 0)

__device__ __forceinline__ unsigned f2bfbits(float x) {
  union { float f; unsigned u; } v; v.f = x;
  return (v.u + 0x7FFFu + ((v.u >> 16) & 1u)) >> 16;
}
__device__ __forceinline__ unsigned packbf(float a, float b) {
  __hip_bfloat162 h2 = __float22bfloat162_rn(make_float2(a, b));
  return *(unsigned*)&h2;
}

// ------- fused normalize: stats + normalize + transpose + bf16 cast --------
// Q (arr==0) is pre-scaled by log2(e): downstream uses exp2(Q.K) == exp(q.k).
__global__ void norm_fused(const float* __restrict__ t_in,
                           const float* __restrict__ s_in,
                           const float* __restrict__ r_in,
                           u16* __restrict__ qn, u16* __restrict__ ksn,
                           u16* __restrict__ krn) {
  __shared__ float tile[256 * 33];
  __shared__ float sums[256], sqs[256];
  __shared__ float mv[32], ivv[32];
  int idx = blockIdx.x;
  int ab = idx >> 7, lt = idx & 127;
  int arr = ab >> 1, b = ab & 1;
  int l0 = lt * 32;
  const float* inp = (arr == 0 ? t_in : arr == 1 ? s_in : r_in) + (size_t)b * CDIM * LPOS;
  u16* outp = (arr == 0 ? qn : arr == 1 ? ksn : krn) + (size_t)b * LPOS * CDIM;
  float scale = (arr == 0) ? 1.4426950408889634f : 1.0f;
  int t = threadIdx.x;
  int cg = t >> 5, l = t & 31;
  float sum = 0.f, sq = 0.f;
#pragma unroll 8
  for (int cc = 0; cc < 32; ++cc) {
    int c = cg * 32 + cc;
    float v = inp[(size_t)c * LPOS + l0 + l];
    tile[c * 33 + l] = v;
    sum += v; sq += v * v;
  }
  sums[t] = sum; sqs[t] = sq;
  __syncthreads();
  if (t < 32) {
    float s = 0.f, q = 0.f;
#pragma unroll
    for (int g = 0; g < 8; ++g) { s += sums[g * 32 + t]; q += sqs[g * 32 + t]; }
    float mean = s * (1.0f / CDIM);
    float nsq = q - s * s * (1.0f / CDIM);
    mv[t] = mean;
    ivv[t] = rsqrtf(fmaxf(nsq, 1e-20f)) * scale;
  }
  __syncthreads();
  int c2 = t & 127, ph = t >> 7;
#pragma unroll 4
  for (int rr = 0; rr < 16; ++rr) {
    int pos = ph + rr * 2;
    float m = mv[pos], iv = ivv[pos];
    float v0 = (tile[(2 * c2) * 33 + pos] - m) * iv;
    float v1 = (tile[(2 * c2 + 1) * 33 + pos] - m) * iv;
    *(unsigned*)&outp[(size_t)(l0 + pos) * CDIM + 2 * c2] = packbf(v0, v1);
  }
}

// ---------------- build combined V tensors (bf16, [C_v][L]) -----------------
// vs: [2][32][4096]   ch: 0..3 src_feats, 4 ones, 5..31 zero
// vr: [2][160][4096]  ch: 0..150 sem, 151..154 ref_feats, 155 ones, 156..159 zero
__global__ void build_v(const float* __restrict__ sf, const float* __restrict__ rf,
                        const float* __restrict__ sem,
                        u16* __restrict__ vs, u16* __restrict__ vr) {
  int t = blockIdx.x * 256 + threadIdx.x;
  const int NVS = 2 * 32 * 4096;
  if (t < NVS) {
    int b = t >> 17;
    int c = (t >> 12) & 31;
    int j = t & 4095;
    float v = (c < 4) ? sf[((size_t)b * 4 + c) * LPOS + j] : (c == 4 ? 1.0f : 0.0f);
    vs[t] = (u16)f2bfbits(v);
  } else {
    int t2 = t - NVS;
    if (t2 < 2 * 160 * 4096) {
      int b = t2 / (160 * 4096);
      int rr = t2 % (160 * 4096);
      int c = rr >> 12, j = rr & 4095;
      float v = (c < 151) ? sem[((size_t)b * 151 + c) * LPOS + j]
              : (c < 155) ? rf[((size_t)b * 4 + (c - 151)) * LPOS + j]
              : (c == 155) ? 1.0f : 0.0f;
      vr[((size_t)b * 160 + c) * LPOS + j] = (u16)f2bfbits(v);
    }
  }
}

// ---------------- fused flash soft-warp ----------------
// S^T orientation: D[m=j][n=i] = sum_c K[j][c] * Q[i][c]
// PV: D[m=c][n=i]  = sum_j V[c][j] * P[j][i]
// R11 (this round): LPT block packing. R9 (deeper pipeline) and R10
// (permlane/setprio) were both NULL -> inner schedule is not the lever; the
// visible inefficiency is block-duration imbalance: ref blocks (16it x 26
// MFMA ~ 416u) vs src (8it x 18 ~ 144u), ratio 2.9, 1536 blocks on 512
// resident slots -> tail skew. Fix: nch_src 16->8 (src = 16it x 18 ~ 288u,
// ratio 1.44) and dispatch ALL ref blocks first: grid = 512 ref + 512 src =
// exactly 2 rounds of the 512 slots (1 ref then 1 src per slot).
// Inner loop identical to R10 (verified).
template <int CT>
__device__ __forceinline__ void flash_body(
    const u16* __restrict__ qb, const u16* __restrict__ kb,
    const u16* __restrict__ vb, float* __restrict__ dst,
    u16 (*lds)[LDSBUF], int wave, int lane, int i_wave, int j_base, int iters) {
  int h = lane >> 5, ln = lane & 31;

  // Q fragments: B[k=c][n=i], lane n=ln, k = kt*16 + h*8 + t
  bf16x8 qf[16];
  const u16* qrow = qb + (size_t)(i_wave + ln) * CDIM;
#pragma unroll
  for (int kt = 0; kt < 16; ++kt)
    qf[kt] = *(const bf16x8*)(qrow + kt * 16 + h * 8);
  // pin: asm results cannot be rematerialized -> qf stays in VGPRs (R8)
#pragma unroll
  for (int kt = 0; kt < 16; ++kt)
    asm volatile("" : "+v"(*(u32x4*)&qf[kt]));

  f32x16 O[CT];
#pragma unroll
  for (int c = 0; c < CT; ++c)
#pragma unroll
    for (int t = 0; t < 16; ++t) O[c][t] = 0.0f;

  // Producer: K 32 rows (XOR-swizzled 16B chunks); ref also V as 10 x 64-row
  // slots over flat [plane(4)][row(160)][8j]. Slot->wave map: s = wave + 4g
  // (counts {3,3,2,2}) so every wave stages >= 6 items (4K + >=2V).
  auto stage = [&](int j0s, int buf) {
#pragma unroll
    for (int g = 0; g < 4; ++g) {
      int G = wave * 4 + g;
      int j = 2 * G + h;
      GLOAD_LDS16(kb + (size_t)(j0s + j) * CDIM + (ln ^ (j & 7)) * 8,
                  &lds[buf][G * 512]);
    }
    if constexpr (CT == 5) {
#pragma unroll
      for (int g = 0; g < 3; ++g) {
        int s = wave + g * 4;               // 0..11, use 0..9
        if (s < 10) {
          int f = s * 64 + lane;            // flat 16B-chunk index 0..639
          int p = f / 160;                  // plane = j-octet
          int c = f - p * 160;              // V channel row
          GLOAD_LDS16(vb + (size_t)c * LPOS + j0s + p * 8,
                      &lds[buf][8192 + s * 512]);
        }
      }
    }
  };

  // Precomputed LDS read bases (buf 0); runtime bo = buf*LDSBUF added per read.
  int kread_base = ln * 256 + 8 * (h ^ (ln & 1));
  int q = (ln >> 1) & 3;
  const u16* ka[4];
#pragma unroll
  for (int m = 0; m < 4; ++m) ka[m] = &lds[0][kread_base + 16 * (m ^ q)];
  // V(ref) addr(kt2,ct,buf) = va + kt2*2560 + ct*256 + bo
  const u16* va = &lds[0][8192 + h * 1280 + ln * 8];

  stage(j_base, 0);
  if (iters > 1) stage(j_base + 32, 1);

  int buf = 0;
  for (int jt = 0; jt < iters; ++jt) {
    int j0 = j_base + jt * 32;
    int bo = buf * LDSBUF;

    // Own stage(jt) completion (oldest in FIFO); keep newer prefetch flying.
    if (jt == iters - 1) {
      asm volatile("s_waitcnt vmcnt(0)" ::: "memory");
    } else if (CT == 5) {
      asm volatile("s_waitcnt vmcnt(6)" ::: "memory");
    } else {
      asm volatile("s_waitcnt vmcnt(4)" ::: "memory");
    }
    __builtin_amdgcn_sched_barrier(0);
    __builtin_amdgcn_s_barrier();      // raw: no vmcnt/lgkm drain
    __builtin_amdgcn_sched_barrier(0);

    // src: consumer V loads FIRST (FIFO: older than the new prefetch)
    bf16x8 vf[2];
    if constexpr (CT == 1) {
#pragma unroll
      for (int kt2 = 0; kt2 < 2; ++kt2)
        vf[kt2] = *(const bf16x8*)(vb + (size_t)ln * LPOS + j0 + (2 * kt2 + h) * 8);
    }
    if (jt + 2 < iters) {
      int b2 = buf ? buf - 1 : 2;        // (buf+2)%3
      stage(j0 + 64, b2);                // producer LAST
    }

    __builtin_amdgcn_s_setprio(1);       // T5: favor compute wave

    // QK: A = K (LDS), B = Q (pinned regs)
    f32x16 Sa, Sb;
#pragma unroll
    for (int t = 0; t < 16; ++t) { Sa[t] = 0.0f; Sb[t] = 0.0f; }
#pragma unroll
    for (int kt = 0; kt < 16; kt += 2) {
      bf16x8 ka0 = *(const bf16x8*)(ka[kt & 3] + 64 * (kt >> 2) + bo);
      Sa = __builtin_amdgcn_mfma_f32_32x32x16_bf16(ka0, qf[kt], Sa, 0, 0, 0);
      bf16x8 ka1 = *(const bf16x8*)(ka[(kt + 1) & 3] + 64 * ((kt + 1) >> 2) + bo);
      Sb = __builtin_amdgcn_mfma_f32_32x32x16_bf16(ka1, qf[kt + 1], Sb, 0, 0, 0);
    }
    // Q was pre-scaled by log2e: exp2(s_hat) == exp(s). Single v_exp_f32.
    f32x16 S;
#pragma unroll
    for (int t = 0; t < 16; ++t) S[t] = EXP2(Sa[t] + Sb[t]);

    // P^T C-layout -> PV B-frags via v_permlane32_swap_b32 (pure VALU):
    // swap(c0,c2): c0 -> [c0.lo, c2.lo^] = u[0], c2 -> [c0.hi_v, c2.hi] = u[2]
    bf16x8 pb[2];
#pragma unroll
    for (int kh = 0; kh < 2; ++kh) {
      unsigned c0 = packbf(S[kh * 8 + 0], S[kh * 8 + 1]);
      unsigned c1 = packbf(S[kh * 8 + 2], S[kh * 8 + 3]);
      unsigned c2 = packbf(S[kh * 8 + 4], S[kh * 8 + 5]);
      unsigned c3 = packbf(S[kh * 8 + 6], S[kh * 8 + 7]);
      asm("v_permlane32_swap_b32 %0, %1" : "+v"(c0), "+v"(c2));
      asm("v_permlane32_swap_b32 %0, %1" : "+v"(c1), "+v"(c3));
      union { unsigned u[4]; bf16x8 v; } tmp;
      tmp.u[0] = c0;
      tmp.u[1] = c1;
      tmp.u[2] = c2;
      tmp.u[3] = c3;
      pb[kh] = tmp.v;
    }

    // PV: A = V (ref: LDS; src: regs), B = P
#pragma unroll
    for (int ct = 0; ct < CT; ++ct)
#pragma unroll
      for (int kt2 = 0; kt2 < 2; ++kt2) {
        bf16x8 vax;
        if constexpr (CT == 5)
          vax = *(const bf16x8*)(va + kt2 * 2560 + ct * 256 + bo);
        else
          vax = vf[kt2];
        O[ct] = __builtin_amdgcn_mfma_f32_32x32x16_bf16(vax, pb[kt2], O[ct], 0, 0, 0);
      }

    __builtin_amdgcn_s_setprio(0);

    buf = (buf == 2) ? 0 : buf + 1;
  }

  // epilogue: D rows = c, cols = i. Trim never-read channels:
  // src uses c<5 (4 feats + ones), ref uses c<156 (151 sem + 4 feats + ones).
  const int climit = (CT == 1) ? 5 : 156;
#pragma unroll
  for (int ct = 0; ct < CT; ++ct)
#pragma unroll
    for (int t = 0; t < 16; ++t) {
      int c = ct * 32 + (t & 3) + 8 * (t >> 2) + 4 * h;
      if (c < climit)
        dst[(size_t)c * LPOS + i_wave + ln] = O[ct][t];
    }
}

// 78 KB LDS, (256,2): full 256-reg budget (R2/R6 proved any tighter cap
// spills qf/O through scratch at a 2x cost). 2 blocks/CU (156 KB LDS).
// Block order: ALL ref blocks first (idx < 64*nch_ref), then src (LPT).
__global__ __launch_bounds__(256, 2) void flash(
    const u16* __restrict__ qn, const u16* __restrict__ ksn, const u16* __restrict__ krn,
    const u16* __restrict__ vs, const u16* __restrict__ vr,
    float* __restrict__ nsrc, float* __restrict__ nref,
    int nch_src, int nch_ref) {
  __shared__ u16 lds[3][LDSBUF];   // 78 KB
  int tid = threadIdx.x;
  int wave = tid >> 6, lane = tid & 63;
  int idx = blockIdx.x;
  int nrefb = 64 * nch_ref;
  if (idx < nrefb) {                 // ref block (longest first)
    int r = idx;
    int chunk = r >> 6, b = (r >> 5) & 1, wgi = r & 31;
    int jchunk = LPOS / nch_ref;
    flash_body<5>(qn + (size_t)b * LPOS * CDIM, krn + (size_t)b * LPOS * CDIM,
                  vr + (size_t)b * 160 * LPOS,
                  nref + (size_t)(chunk * 2 + b) * 160 * LPOS,
                  lds, wave, lane, wgi * 128 + wave * 32, chunk * jchunk,
                  jchunk / 32);
  } else {                           // src block
    int r = idx - nrefb;
    int chunk = r >> 6, b = (r >> 5) & 1, wgi = r & 31;
    int jchunk = LPOS / nch_src;
    flash_body<1>(qn + (size_t)b * LPOS * CDIM, ksn + (size_t)b * LPOS * CDIM,
                  vs + (size_t)b * 32 * LPOS,
                  nsrc + (size_t)(chunk * 2 + b) * 32 * LPOS,
                  lds, wave, lane, wgi * 128 + wave * 32, chunk * jchunk,
                  jchunk / 32);
  }
}

// ---------------- finalize: sum chunks, divide by ones-channel --------------
// float4-vectorized: 325632 float4 outputs (= 1302528 f32).
__global__ void finalize(const float* __restrict__ nsrc, const float* __restrict__ nref,
                         float* __restrict__ out, int nch_src, int nch_ref) {
  int v = blockIdx.x * 256 + threadIdx.x;
  if (v >= 325632) return;
  float nx = 0.f, ny = 0.f, nz = 0.f, nw = 0.f;
  float dx = 0.f, dy = 0.f, dz = 0.f, dw = 0.f;
  if (v < 8192) {                         // warped_src_feat [2][4][4096]
    int b = v >> 12, c = (v >> 10) & 3, i4 = v & 1023;
    for (int k = 0; k < nch_src; ++k) {
      const float* base = nsrc + ((size_t)(k * 2 + b) * 32) * LPOS;
      float4 n4 = ((const float4*)(base + (size_t)c * LPOS))[i4];
      float4 d4 = ((const float4*)(base + (size_t)4 * LPOS))[i4];
      nx += n4.x; ny += n4.y; nz += n4.z; nw += n4.w;
      dx += d4.x; dy += d4.y; dz += d4.z; dw += d4.w;
    }
  } else if (v < 16384) {                 // warped_ref_feat [2][4][4096]
    int v1 = v - 8192;
    int b = v1 >> 12, c = (v1 >> 10) & 3, i4 = v1 & 1023;
    for (int k = 0; k < nch_ref; ++k) {
      const float* base = nref + ((size_t)(k * 2 + b) * 160) * LPOS;
      float4 n4 = ((const float4*)(base + (size_t)(151 + c) * LPOS))[i4];
      float4 d4 = ((const float4*)(base + (size_t)155 * LPOS))[i4];
      nx += n4.x; ny += n4.y; nz += n4.z; nw += n4.w;
      dx += d4.x; dy += d4.y; dz += d4.z; dw += d4.w;
    }
  } else {                                // warped_ref_seg [2][151][4096]
    int v2 = v - 16384;
    int b = v2 / 154624;                  // 151 * 1024
    int rr = v2 - b * 154624;
    int c = rr >> 10, i4 = rr & 1023;
    for (int k = 0; k < nch_ref; ++k) {
      const float* base = nref + ((size_t)(k * 2 + b) * 160) * LPOS;
      float4 n4 = ((const float4*)(base + (size_t)c * LPOS))[i4];
      float4 d4 = ((const float4*)(base + (size_t)155 * LPOS))[i4];
      nx += n4.x; ny += n4.y; nz += n4.z; nw += n4.w;
      dx += d4.x; dy += d4.y; dz += d4.z; dw += d4.w;
    }
  }
  float4 r;
  r.x = nx / dx; r.y = ny / dy; r.z = nz / dz; r.w = nw / dw;
  ((float4*)out)[v] = r;
}

extern "C" void kernel_launch(void* const* d_in, const int* in_sizes, int n_in,
                              void* d_out, int out_size, void* d_ws, size_t ws_size,
                              hipStream_t stream) {
  const float* trg  = (const float*)d_in[0];
  const float* srcp = (const float*)d_in[1];
  const float* refp = (const float*)d_in[2];
  const float* sfeat = (const float*)d_in[3];
  const float* rfeat = (const float*)d_in[4];
  const float* rsem  = (const float*)d_in[5];
  float* out = (float*)d_out;

  char* ws = (char*)d_ws;
  size_t o = 0;
  auto alloc = [&](size_t bytes) -> char* {
    char* p = ws + o;
    o += (bytes + 255) & ~(size_t)255;
    return p;
  };
  u16* qn  = (u16*)alloc(2ull * LPOS * CDIM * 2);
  u16* ksn = (u16*)alloc(2ull * LPOS * CDIM * 2);
  u16* krn = (u16*)alloc(2ull * LPOS * CDIM * 2);
  u16* vs  = (u16*)alloc(2ull * 32 * LPOS * 2);
  u16* vr  = (u16*)alloc(2ull * 160 * LPOS * 2);

  size_t fixed = o;
  int nch_ref = 8;                       // nch_src = nch_ref (uniform blocks)
  for (;;) {
    size_t need = fixed + 512 +
                  (size_t)nch_ref * 2 * 32 * LPOS * 4 +
                  (size_t)nch_ref * 2 * 160 * LPOS * 4;
    if (need <= ws_size || nch_ref == 1) break;
    nch_ref >>= 1;
  }
  int nch_src = nch_ref;
  float* nsrc = (float*)alloc((size_t)nch_src * 2 * 32 * LPOS * 4);
  float* nref = (float*)alloc((size_t)nch_ref * 2 * 160 * LPOS * 4);

  hipLaunchKernelGGL(norm_fused, dim3(768), dim3(256), 0, stream,
                     trg, srcp, refp, qn, ksn, krn);
  hipLaunchKernelGGL(build_v, dim3(6144), dim3(256), 0, stream,
                     sfeat, rfeat, rsem, vs, vr);
  hipLaunchKernelGGL(flash, dim3(64 * (nch_ref + nch_src)), dim3(256), 0, stream,
                     qn, ksn, krn, vs, vr, nsrc, nref, nch_src, nch_ref);
  hipLaunchKernelGGL(finalize, dim3(1272), dim3(256), 0, stream,
                     nsrc, nref, out, nch_src, nch_ref);
}

// Round 5
// 145.316 us; speedup vs baseline: 1.1664x; 1.0123x over previous
//
#include <hip/hip_runtime.h>
#include <hip/hip_bf16.h>
#include <cstdint>
#include <cstddef>

typedef unsigned short u16;
typedef __attribute__((ext_vector_type(8))) __bf16 bf16x8;
typedef __attribute__((ext_vector_type(4))) unsigned u32x4;
typedef __attribute__((ext_vector_type(16))) float f32x16;

#define LPOS 4096
#define CDIM 256
// per-buffer LDS (u16): 8192 K (32 rows x 256c) + 5120 V (4 planes x 160 rows x 8j)
#define LDSBUF 13312

#if __has_builtin(__builtin_amdgcn_exp2f)
#define EXP2(x) __builtin_amdgcn_exp2f(x)
#else
#define EXP2(x) exp2f(x)
#endif

// async global->LDS 16B: LDS dst must be wave-uniform base + lane*16
#define GLOAD_LDS16(g, l)                                                      \
  __builtin_amdgcn_global_load_lds(                                            \
      (const __attribute__((address_space(1))) void*)(g),                      \
      (__attribute__((address_space(3))) void*)(l), 16, 0, 0)

__device__ __forceinline__ unsigned f2bfbits(float x) {
  union { float f; unsigned u; } v; v.f = x;
  return (v.u + 0x7FFFu + ((v.u >> 16) & 1u)) >> 16;
}
__device__ __forceinline__ unsigned packbf(float a, float b) {
  __hip_bfloat162 h2 = __float22bfloat162_rn(make_float2(a, b));
  return *(unsigned*)&h2;
}

// ------- fused normalize: stats + normalize + transpose + bf16 cast --------
// Q (arr==0) is pre-scaled by log2(e): downstream uses exp2(Q.K) == exp(q.k).
__global__ void norm_fused(const float* __restrict__ t_in,
                           const float* __restrict__ s_in,
                           const float* __restrict__ r_in,
                           u16* __restrict__ qn, u16* __restrict__ ksn,
                           u16* __restrict__ krn) {
  __shared__ float tile[256 * 33];
  __shared__ float sums[256], sqs[256];
  __shared__ float mv[32], ivv[32];
  int idx = blockIdx.x;
  int ab = idx >> 7, lt = idx & 127;
  int arr = ab >> 1, b = ab & 1;
  int l0 = lt * 32;
  const float* inp = (arr == 0 ? t_in : arr == 1 ? s_in : r_in) + (size_t)b * CDIM * LPOS;
  u16* outp = (arr == 0 ? qn : arr == 1 ? ksn : krn) + (size_t)b * LPOS * CDIM;
  float scale = (arr == 0) ? 1.4426950408889634f : 1.0f;
  int t = threadIdx.x;
  int cg = t >> 5, l = t & 31;
  float sum = 0.f, sq = 0.f;
#pragma unroll 8
  for (int cc = 0; cc < 32; ++cc) {
    int c = cg * 32 + cc;
    float v = inp[(size_t)c * LPOS + l0 + l];
    tile[c * 33 + l] = v;
    sum += v; sq += v * v;
  }
  sums[t] = sum; sqs[t] = sq;
  __syncthreads();
  if (t < 32) {
    float s = 0.f, q = 0.f;
#pragma unroll
    for (int g = 0; g < 8; ++g) { s += sums[g * 32 + t]; q += sqs[g * 32 + t]; }
    float mean = s * (1.0f / CDIM);
    float nsq = q - s * s * (1.0f / CDIM);
    mv[t] = mean;
    ivv[t] = rsqrtf(fmaxf(nsq, 1e-20f)) * scale;
  }
  __syncthreads();
  int c2 = t & 127, ph = t >> 7;
#pragma unroll 4
  for (int rr = 0; rr < 16; ++rr) {
    int pos = ph + rr * 2;
    float m = mv[pos], iv = ivv[pos];
    float v0 = (tile[(2 * c2) * 33 + pos] - m) * iv;
    float v1 = (tile[(2 * c2 + 1) * 33 + pos] - m) * iv;
    *(unsigned*)&outp[(size_t)(l0 + pos) * CDIM + 2 * c2] = packbf(v0, v1);
  }
}

// ---------------- build combined V tensors (bf16, [C_v][L]) -----------------
// vs: [2][32][4096]   ch: 0..3 src_feats, 4 ones, 5..31 zero
// vr: [2][160][4096]  ch: 0..150 sem, 151..154 ref_feats, 155 ones, 156..159 zero
__global__ void build_v(const float* __restrict__ sf, const float* __restrict__ rf,
                        const float* __restrict__ sem,
                        u16* __restrict__ vs, u16* __restrict__ vr) {
  int t = blockIdx.x * 256 + threadIdx.x;
  const int NVS = 2 * 32 * 4096;
  if (t < NVS) {
    int b = t >> 17;
    int c = (t >> 12) & 31;
    int j = t & 4095;
    float v = (c < 4) ? sf[((size_t)b * 4 + c) * LPOS + j] : (c == 4 ? 1.0f : 0.0f);
    vs[t] = (u16)f2bfbits(v);
  } else {
    int t2 = t - NVS;
    if (t2 < 2 * 160 * 4096) {
      int b = t2 / (160 * 4096);
      int rr = t2 % (160 * 4096);
      int c = rr >> 12, j = rr & 4095;
      float v = (c < 151) ? sem[((size_t)b * 151 + c) * LPOS + j]
              : (c < 155) ? rf[((size_t)b * 4 + (c - 151)) * LPOS + j]
              : (c == 155) ? 1.0f : 0.0f;
      vr[((size_t)b * 160 + c) * LPOS + j] = (u16)f2bfbits(v);
    }
  }
}

// ---------------- fused flash soft-warp ----------------
// S^T orientation: D[m=j][n=i] = sum_c K[j][c] * Q[i][c]
// PV: D[m=c][n=i]  = sum_j V[c][j] * P[j][i]
// R12: deferred-softmax pipeline (T15). R11's LPT packing was the first WIN
// (65us); accounting shows remaining gap is the serial per-iter chain
// QK -> exp -> pack -> PV with nothing to overlap at 2 waves/SIMD.
// Restructure: iter jt computes QK(jt) -> Sp; exp/pack/PV of (jt-1) runs in
// the SAME iter, independent of QK(jt) -> compiler interleaves the VALU tail
// under QK's MFMA issue, and PV's V ds_reads get an extra iter of slack.
//  - depth-1 prefetch (R9 proved depth-2 NULL): 3 buffers hold the 3 live
//    roles {PV(jt-1), QK(jt), stage(jt+1)} - disjoint mod 3.
//  - races: stage(jt+1) overwrites buf((jt+1)%3), last PV-read in iter jt-1,
//    proven done by barrier(jt). Reads proven by own vmcnt(0) + barrier.
//  - src vf (V-from-global) loads issue BEFORE stage so the compiler's wait
//    for vf leaves the fresh prefetch in flight (FIFO vmcnt).
//  - tail after loop: exp/pack/PV of the last tile (staged+proven at last
//    iter top; no further LDS writes -> no barrier needed).
template <int CT>
__device__ __forceinline__ void flash_body(
    const u16* __restrict__ qb, const u16* __restrict__ kb,
    const u16* __restrict__ vb, float* __restrict__ dst,
    u16 (*lds)[LDSBUF], int wave, int lane, int i_wave, int j_base, int iters) {
  int h = lane >> 5, ln = lane & 31;

  // Q fragments: B[k=c][n=i], lane n=ln, k = kt*16 + h*8 + t
  bf16x8 qf[16];
  const u16* qrow = qb + (size_t)(i_wave + ln) * CDIM;
#pragma unroll
  for (int kt = 0; kt < 16; ++kt)
    qf[kt] = *(const bf16x8*)(qrow + kt * 16 + h * 8);
  // pin: asm results cannot be rematerialized -> qf stays in VGPRs (R8)
#pragma unroll
  for (int kt = 0; kt < 16; ++kt)
    asm volatile("" : "+v"(*(u32x4*)&qf[kt]));

  f32x16 O[CT];
#pragma unroll
  for (int c = 0; c < CT; ++c)
#pragma unroll
    for (int t = 0; t < 16; ++t) O[c][t] = 0.0f;

  // Producer: K 32 rows (XOR-swizzled 16B chunks); ref also V as 10 x 64-row
  // slots over flat [plane(4)][row(160)][8j]. Slot->wave map: s = wave + 4g
  // (counts {3,3,2,2}).
  auto stage = [&](int j0s, int buf) {
#pragma unroll
    for (int g = 0; g < 4; ++g) {
      int G = wave * 4 + g;
      int j = 2 * G + h;
      GLOAD_LDS16(kb + (size_t)(j0s + j) * CDIM + (ln ^ (j & 7)) * 8,
                  &lds[buf][G * 512]);
    }
    if constexpr (CT == 5) {
#pragma unroll
      for (int g = 0; g < 3; ++g) {
        int s = wave + g * 4;               // 0..11, use 0..9
        if (s < 10) {
          int f = s * 64 + lane;            // flat 16B-chunk index 0..639
          int p = f / 160;                  // plane = j-octet
          int c = f - p * 160;              // V channel row
          GLOAD_LDS16(vb + (size_t)c * LPOS + j0s + p * 8,
                      &lds[buf][8192 + s * 512]);
        }
      }
    }
  };

  // Precomputed LDS read bases (buf 0); runtime bo = buf*LDSBUF added per read.
  int kread_base = ln * 256 + 8 * (h ^ (ln & 1));
  int q = (ln >> 1) & 3;
  const u16* ka[4];
#pragma unroll
  for (int m = 0; m < 4; ++m) ka[m] = &lds[0][kread_base + 16 * (m ^ q)];
  // V(ref) addr(kt2,ct,buf) = va + kt2*2560 + ct*256 + bo
  const u16* va = &lds[0][8192 + h * 1280 + ln * 8];

  // Deferred-softmax helper: exp/pack/PV for the PREVIOUS tile.
  f32x16 Sp;                // raw scores of tile jt-1 (pre-exp)
#pragma unroll
  for (int t = 0; t < 16; ++t) Sp[t] = 0.0f;

  auto finish_prev = [&](int pbo, const bf16x8* vfp) {
    f32x16 S;
#pragma unroll
    for (int t = 0; t < 16; ++t) S[t] = EXP2(Sp[t]);
    bf16x8 pb[2];
#pragma unroll
    for (int kh = 0; kh < 2; ++kh) {
      unsigned c0 = packbf(S[kh * 8 + 0], S[kh * 8 + 1]);
      unsigned c1 = packbf(S[kh * 8 + 2], S[kh * 8 + 3]);
      unsigned c2 = packbf(S[kh * 8 + 4], S[kh * 8 + 5]);
      unsigned c3 = packbf(S[kh * 8 + 6], S[kh * 8 + 7]);
      asm("v_permlane32_swap_b32 %0, %1" : "+v"(c0), "+v"(c2));
      asm("v_permlane32_swap_b32 %0, %1" : "+v"(c1), "+v"(c3));
      union { unsigned u[4]; bf16x8 v; } tmp;
      tmp.u[0] = c0;
      tmp.u[1] = c1;
      tmp.u[2] = c2;
      tmp.u[3] = c3;
      pb[kh] = tmp.v;
    }
#pragma unroll
    for (int ct = 0; ct < CT; ++ct)
#pragma unroll
      for (int kt2 = 0; kt2 < 2; ++kt2) {
        bf16x8 vax;
        if constexpr (CT == 5)
          vax = *(const bf16x8*)(va + kt2 * 2560 + ct * 256 + pbo);
        else
          vax = vfp[kt2];
        O[ct] = __builtin_amdgcn_mfma_f32_32x32x16_bf16(vax, pb[kt2], O[ct], 0, 0, 0);
      }
  };

  stage(j_base, 0);                  // depth-1 prefetch

  int buf = 0, pbo = 0;
  for (int jt = 0; jt < iters; ++jt) {
    int j0 = j_base + jt * 32;
    int bo = buf * LDSBUF;

    // Own stage(jt) is the only outstanding VM group at iter top.
    asm volatile("s_waitcnt vmcnt(0)" ::: "memory");
    __builtin_amdgcn_sched_barrier(0);
    __builtin_amdgcn_s_barrier();      // raw: no vmcnt/lgkm drain
    __builtin_amdgcn_sched_barrier(0);

    // src: V regs for the PREVIOUS tile (consumed by finish_prev this iter).
    // Issued BEFORE stage: compiler's wait for vf keeps prefetch in flight.
    bf16x8 vf[2];
    if (CT == 1 && jt >= 1) {
#pragma unroll
      for (int kt2 = 0; kt2 < 2; ++kt2)
        vf[kt2] = *(const bf16x8*)(vb + (size_t)ln * LPOS + (j0 - 32) + (2 * kt2 + h) * 8);
    }
    if (jt + 1 < iters) {
      int nb = (buf == 2) ? 0 : buf + 1;
      stage(j0 + 32, nb);              // producer LAST
    }

    __builtin_amdgcn_s_setprio(1);

    // QK(jt): A = K (LDS buf jt), B = Q (pinned regs)
    f32x16 Sa, Sb;
#pragma unroll
    for (int t = 0; t < 16; ++t) { Sa[t] = 0.0f; Sb[t] = 0.0f; }
#pragma unroll
    for (int kt = 0; kt < 16; kt += 2) {
      bf16x8 ka0 = *(const bf16x8*)(ka[kt & 3] + 64 * (kt >> 2) + bo);
      Sa = __builtin_amdgcn_mfma_f32_32x32x16_bf16(ka0, qf[kt], Sa, 0, 0, 0);
      bf16x8 ka1 = *(const bf16x8*)(ka[(kt + 1) & 3] + 64 * ((kt + 1) >> 2) + bo);
      Sb = __builtin_amdgcn_mfma_f32_32x32x16_bf16(ka1, qf[kt + 1], Sb, 0, 0, 0);
    }

    // finish tile jt-1 (independent of QK(jt) -> overlaps under MFMA issue)
    if (jt >= 1) finish_prev(pbo, vf);

    // hand off raw scores for next iter
#pragma unroll
    for (int t = 0; t < 16; ++t) Sp[t] = Sa[t] + Sb[t];

    __builtin_amdgcn_s_setprio(0);

    pbo = bo;
    buf = (buf == 2) ? 0 : buf + 1;
  }

  // tail: finish the last tile (its buffer is never overwritten post-loop)
  {
    bf16x8 vf[2];
    if constexpr (CT == 1) {
      int jlast = j_base + (iters - 1) * 32;
#pragma unroll
      for (int kt2 = 0; kt2 < 2; ++kt2)
        vf[kt2] = *(const bf16x8*)(vb + (size_t)ln * LPOS + jlast + (2 * kt2 + h) * 8);
    }
    finish_prev(pbo, vf);
  }

  // epilogue: D rows = c, cols = i. Trim never-read channels:
  // src uses c<5 (4 feats + ones), ref uses c<156 (151 sem + 4 feats + ones).
  const int climit = (CT == 1) ? 5 : 156;
#pragma unroll
  for (int ct = 0; ct < CT; ++ct)
#pragma unroll
    for (int t = 0; t < 16; ++t) {
      int c = ct * 32 + (t & 3) + 8 * (t >> 2) + 4 * h;
      if (c < climit)
        dst[(size_t)c * LPOS + i_wave + ln] = O[ct][t];
    }
}

// 78 KB LDS, (256,2): full 256-reg budget (R2/R6 proved any tighter cap
// spills qf/O through scratch at a 2x cost). 2 blocks/CU (156 KB LDS).
// Block order: ALL ref blocks first (idx < 64*nch_ref), then src (LPT).
__global__ __launch_bounds__(256, 2) void flash(
    const u16* __restrict__ qn, const u16* __restrict__ ksn, const u16* __restrict__ krn,
    const u16* __restrict__ vs, const u16* __restrict__ vr,
    float* __restrict__ nsrc, float* __restrict__ nref,
    int nch_src, int nch_ref) {
  __shared__ u16 lds[3][LDSBUF];   // 78 KB
  int tid = threadIdx.x;
  int wave = tid >> 6, lane = tid & 63;
  int idx = blockIdx.x;
  int nrefb = 64 * nch_ref;
  if (idx < nrefb) {                 // ref block (longest first)
    int r = idx;
    int chunk = r >> 6, b = (r >> 5) & 1, wgi = r & 31;
    int jchunk = LPOS / nch_ref;
    flash_body<5>(qn + (size_t)b * LPOS * CDIM, krn + (size_t)b * LPOS * CDIM,
                  vr + (size_t)b * 160 * LPOS,
                  nref + (size_t)(chunk * 2 + b) * 160 * LPOS,
                  lds, wave, lane, wgi * 128 + wave * 32, chunk * jchunk,
                  jchunk / 32);
  } else {                           // src block
    int r = idx - nrefb;
    int chunk = r >> 6, b = (r >> 5) & 1, wgi = r & 31;
    int jchunk = LPOS / nch_src;
    flash_body<1>(qn + (size_t)b * LPOS * CDIM, ksn + (size_t)b * LPOS * CDIM,
                  vs + (size_t)b * 32 * LPOS,
                  nsrc + (size_t)(chunk * 2 + b) * 32 * LPOS,
                  lds, wave, lane, wgi * 128 + wave * 32, chunk * jchunk,
                  jchunk / 32);
  }
}

// ---------------- finalize: sum chunks, divide by ones-channel --------------
// float4-vectorized: 325632 float4 outputs (= 1302528 f32).
__global__ void finalize(const float* __restrict__ nsrc, const float* __restrict__ nref,
                         float* __restrict__ out, int nch_src, int nch_ref) {
  int v = blockIdx.x * 256 + threadIdx.x;
  if (v >= 325632) return;
  float nx = 0.f, ny = 0.f, nz = 0.f, nw = 0.f;
  float dx = 0.f, dy = 0.f, dz = 0.f, dw = 0.f;
  if (v < 8192) {                         // warped_src_feat [2][4][4096]
    int b = v >> 12, c = (v >> 10) & 3, i4 = v & 1023;
    for (int k = 0; k < nch_src; ++k) {
      const float* base = nsrc + ((size_t)(k * 2 + b) * 32) * LPOS;
      float4 n4 = ((const float4*)(base + (size_t)c * LPOS))[i4];
      float4 d4 = ((const float4*)(base + (size_t)4 * LPOS))[i4];
      nx += n4.x; ny += n4.y; nz += n4.z; nw += n4.w;
      dx += d4.x; dy += d4.y; dz += d4.z; dw += d4.w;
    }
  } else if (v < 16384) {                 // warped_ref_feat [2][4][4096]
    int v1 = v - 8192;
    int b = v1 >> 12, c = (v1 >> 10) & 3, i4 = v1 & 1023;
    for (int k = 0; k < nch_ref; ++k) {
      const float* base = nref + ((size_t)(k * 2 + b) * 160) * LPOS;
      float4 n4 = ((const float4*)(base + (size_t)(151 + c) * LPOS))[i4];
      float4 d4 = ((const float4*)(base + (size_t)155 * LPOS))[i4];
      nx += n4.x; ny += n4.y; nz += n4.z; nw += n4.w;
      dx += d4.x; dy += d4.y; dz += d4.z; dw += d4.w;
    }
  } else {                                // warped_ref_seg [2][151][4096]
    int v2 = v - 16384;
    int b = v2 / 154624;                  // 151 * 1024
    int rr = v2 - b * 154624;
    int c = rr >> 10, i4 = rr & 1023;
    for (int k = 0; k < nch_ref; ++k) {
      const float* base = nref + ((size_t)(k * 2 + b) * 160) * LPOS;
      float4 n4 = ((const float4*)(base + (size_t)c * LPOS))[i4];
      float4 d4 = ((const float4*)(base + (size_t)155 * LPOS))[i4];
      nx += n4.x; ny += n4.y; nz += n4.z; nw += n4.w;
      dx += d4.x; dy += d4.y; dz += d4.z; dw += d4.w;
    }
  }
  float4 r;
  r.x = nx / dx; r.y = ny / dy; r.z = nz / dz; r.w = nw / dw;
  ((float4*)out)[v] = r;
}

extern "C" void kernel_launch(void* const* d_in, const int* in_sizes, int n_in,
                              void* d_out, int out_size, void* d_ws, size_t ws_size,
                              hipStream_t stream) {
  const float* trg  = (const float*)d_in[0];
  const float* srcp = (const float*)d_in[1];
  const float* refp = (const float*)d_in[2];
  const float* sfeat = (const float*)d_in[3];
  const float* rfeat = (const float*)d_in[4];
  const float* rsem  = (const float*)d_in[5];
  float* out = (float*)d_out;

  char* ws = (char*)d_ws;
  size_t o = 0;
  auto alloc = [&](size_t bytes) -> char* {
    char* p = ws + o;
    o += (bytes + 255) & ~(size_t)255;
    return p;
  };
  u16* qn  = (u16*)alloc(2ull * LPOS * CDIM * 2);
  u16* ksn = (u16*)alloc(2ull * LPOS * CDIM * 2);
  u16* krn = (u16*)alloc(2ull * LPOS * CDIM * 2);
  u16* vs  = (u16*)alloc(2ull * 32 * LPOS * 2);
  u16* vr  = (u16*)alloc(2ull * 160 * LPOS * 2);

  size_t fixed = o;
  int nch_ref = 8;                       // nch_src = nch_ref (uniform blocks)
  for (;;) {
    size_t need = fixed + 512 +
                  (size_t)nch_ref * 2 * 32 * LPOS * 4 +
                  (size_t)nch_ref * 2 * 160 * LPOS * 4;
    if (need <= ws_size || nch_ref == 1) break;
    nch_ref >>= 1;
  }
  int nch_src = nch_ref;
  float* nsrc = (float*)alloc((size_t)nch_src * 2 * 32 * LPOS * 4);
  float* nref = (float*)alloc((size_t)nch_ref * 2 * 160 * LPOS * 4);

  hipLaunchKernelGGL(norm_fused, dim3(768), dim3(256), 0, stream,
                     trg, srcp, refp, qn, ksn, krn);
  hipLaunchKernelGGL(build_v, dim3(6144), dim3(256), 0, stream,
                     sfeat, rfeat, rsem, vs, vr);
  hipLaunchKernelGGL(flash, dim3(64 * (nch_ref + nch_src)), dim3(256), 0, stream,
                     qn, ksn, krn, vs, vr, nsrc, nref, nch_src, nch_ref);
  hipLaunchKernelGGL(finalize, dim3(1272), dim3(256), 0, stream,
                     nsrc, nref, out, nch_src, nch_ref);
}